// Round 5
// baseline (309.707 us; speedup 1.0000x reference)
//
#include <hip/hip_runtime.h>
#include <math.h>

// ---------------------------------------------------------------------------
// TemporalGCN: 2-layer LSTM (per-node sequences) -> 2 GCN rounds -> edge MLP.
//
// R4 post-mortem: lstm kernels ~44 us each; cost = 24 multi-wave barriers on
// the serial recurrence path. R5: ONE WAVE per sequence, lane u owns gate
// rows {u,64+u,128+u,192+u} = i,f,g,o of unit u -> c/h update fully in-lane,
// h broadcast via within-wave LDS (in-order DS pipe, no s_barrier needed).
// Also: wsum/gcn0/gcn1/uv are row-local -> fused into one k_node kernel.
// All FP accumulation orders preserved from the R4 kernel (absmax was 0.0).
// ---------------------------------------------------------------------------

#define Hd   64
#define Ed   5
#define Fd   6
#define Bd   8
#define Wd   12
#define Nd   200
#define NSEQ (Bd*Nd)        // 1600 sequences (b,n)
#define NG   (4*Hd)         // 256 gate rows
#define NEDGE (Bd*Nd*Nd)    // 320000 edges
#define LNEPS 1e-5f

__device__ __forceinline__ float sigm(float x) { return 1.0f / (1.0f + __expf(-x)); }
__device__ __forceinline__ float tanh_fast(float x) {
  float ax = fabsf(x);
  float t  = __expf(-2.0f * ax);
  float r  = (1.0f - t) / (1.0f + t);
  return copysignf(r, x);
}

// --------------------------------------------------------------------------
// Transpose Wih1 (256x64) -> Wt1 (64x256) so xproj1 can do contiguous
// scalar loads of a k-row.
__global__ __launch_bounds__(256) void k_prep(const float* __restrict__ Wih1,
                                              float* __restrict__ Wt1) {
  int k = blockIdx.x;          // 0..63
  int j = threadIdx.x;         // 0..255
  Wt1[k * NG + j] = Wih1[j * Hd + k];
}

// --------------------------------------------------------------------------
// LSTM layer 0. 1600 blocks x 64 threads (ONE wave per sequence).
// Lane u holds Whh0 rows {u,64+u,128+u,192+u} (256 VGPRs) -> i,f,g,o of
// unit u computed in-lane; h broadcast via LDS float4 reads (same-address
// across lanes = free). No multi-wave barriers on the recurrence path.
__global__ __launch_bounds__(64, 1) void k_lstm0(
    const float* __restrict__ nf,                       // (B,W,N,F)
    const float* __restrict__ Wih0, const float* __restrict__ Whh0,
    const float* __restrict__ bih0, const float* __restrict__ bhh0,
    float* __restrict__ y0)                             // (NSEQ, W, H)
{
  __shared__ float x_sh[Wd * Fd];   // 72
  __shared__ float h_sh[Hd];        // 64

  const int u   = threadIdx.x;      // 0..63 = unit index
  const int seq = blockIdx.x;
  const int b = seq / Nd, n = seq % Nd;

  for (int idx = u; idx < Wd * Fd; idx += 64) {
    int t = idx / Fd, f = idx % Fd;
    x_sh[idx] = nf[((b * Wd + t) * Nd + n) * Fd + f];
  }
  h_sh[u] = 0.f;

  float4 wh[4][16];                 // rows g*64+u of Whh0
  #pragma unroll
  for (int g = 0; g < 4; ++g) {
    const float4* wrow = (const float4*)(Whh0 + (g * 64 + u) * Hd);
    #pragma unroll
    for (int q = 0; q < 16; ++q) wh[g][q] = wrow[q];
  }
  float wx[4][Fd];
  #pragma unroll
  for (int g = 0; g < 4; ++g)
    #pragma unroll
    for (int f = 0; f < Fd; ++f) wx[g][f] = Wih0[(g * 64 + u) * Fd + f];
  float bias[4];
  #pragma unroll
  for (int g = 0; g < 4; ++g) bias[g] = bih0[g * 64 + u] + bhh0[g * 64 + u];

  float c = 0.f;
  __syncthreads();                  // 1 wave: cheap

  for (int t = 0; t < Wd; ++t) {
    float xv[Fd];
    #pragma unroll
    for (int f = 0; f < Fd; ++f) xv[f] = x_sh[t * Fd + f];   // broadcast
    float4 hv[16];
    const float4* h4 = (const float4*)h_sh;
    #pragma unroll
    for (int q = 0; q < 16; ++q) hv[q] = h4[q];              // broadcast

    float g4[4];
    #pragma unroll
    for (int g = 0; g < 4; ++g) {
      float a0 = bias[g], a1 = 0.f, a2 = 0.f, a3 = 0.f;
      #pragma unroll
      for (int f = 0; f < Fd; ++f) a1 += xv[f] * wx[g][f];
      #pragma unroll
      for (int q = 0; q < 16; ++q) {
        float d = hv[q].x * wh[g][q].x + hv[q].y * wh[g][q].y +
                  hv[q].z * wh[g][q].z + hv[q].w * wh[g][q].w;
        if ((q & 3) == 0) a0 += d; else if ((q & 3) == 1) a1 += d;
        else if ((q & 3) == 2) a2 += d; else a3 += d;
      }
      float acc = (a0 + a1) + (a2 + a3);
      g4[g] = (g == 2) ? tanh_fast(acc) : sigm(acc);
    }
    c = g4[1] * c + g4[0] * g4[2];           // f*c + i*g
    float h = g4[3] * tanh_fast(c);          // o*tanh(c)
    h_sh[u] = h;
    __syncthreads();                         // 1-wave barrier: ordering only
    y0[seq * (Wd * Hd) + t * Hd + u] = h;
  }
}

// --------------------------------------------------------------------------
// G1 = y0 @ Wih1.T + (bih1+bhh1): (19200 x 64) @ (64 x 256).
// 300 blocks x 256 thr; lane = row, wave = 64-col slab (wave-uniform cols ->
// weights via SCALAR loads; VALU-bound). Output transposed through a 2-tile
// osh in two passes (LDS total 49.9 KB < 64 KB static limit).
__global__ __launch_bounds__(256) void k_xproj1(
    const float* __restrict__ y0,    // rows = seq*12+t
    const float* __restrict__ Wt1,   // (64,256) transposed Wih1
    const float* __restrict__ bih1, const float* __restrict__ bhh1,
    float* __restrict__ G1)          // (19200, 256)
{
  __shared__ float ysh[64 * 65];        // [r][k] pad-65: conflict-free
  __shared__ float osh[2 * 64 * 65];    // two 64x64 out tiles, pad-65

  const int tid  = threadIdx.x;
  const int row0 = blockIdx.x * 64;
  for (int idx = tid; idx < 64 * 64; idx += 256) {
    int r = idx >> 6, k = idx & 63;
    ysh[r * 65 + k] = y0[(row0 + r) * Hd + k];
  }
  __syncthreads();

  const int w = __builtin_amdgcn_readfirstlane(tid >> 6);  // force uniform
  const int r = tid & 63;
  float acc[64];
  #pragma unroll
  for (int c = 0; c < 64; ++c) acc[c] = 0.f;

  const float* wbase = Wt1 + (w << 6);
  #pragma unroll 2
  for (int k = 0; k < 64; ++k) {
    float yv = ysh[r * 65 + k];
    const float* wk = wbase + k * NG;    // uniform address -> s_load
    #pragma unroll
    for (int c = 0; c < 64; ++c) acc[c] = fmaf(yv, wk[c], acc[c]);
  }
  #pragma unroll
  for (int c = 0; c < 64; ++c) acc[c] += bih1[(w << 6) + c] + bhh1[(w << 6) + c];

  // Two passes: waves {0,1} then {2,3} dump 64x64 tiles; everyone stores.
  #pragma unroll
  for (int p = 0; p < 2; ++p) {
    __syncthreads();
    if ((w >> 1) == p) {
      float* orow = osh + ((w & 1) * 64 + r) * 65;
      #pragma unroll
      for (int c = 0; c < 64; ++c) orow[c] = acc[c];  // stride-65: no conflict
    }
    __syncthreads();
    for (int idx = tid; idx < 2 * 64 * 64; idx += 256) {
      int c  = idx & 127;              // col within this 128-col slab
      int rr = idx >> 7;               // row 0..63
      G1[(row0 + rr) * NG + p * 128 + c] =
          osh[((c >> 6) * 64 + rr) * 65 + (c & 63)];   // lanes stride-1: free
    }
  }
}

// --------------------------------------------------------------------------
// LSTM layer 1 recurrence (K=64; input proj precomputed in G1). 1600 blocks
// x 64 threads, one wave per sequence, same layout as k_lstm0. G1 rows
// prefetched one timestep ahead (4 coalesced dword loads per step).
__global__ __launch_bounds__(64, 1) void k_lstm1(
    const float* __restrict__ G1,
    const float* __restrict__ Whh1,
    float* __restrict__ hout)        // (NSEQ, H)
{
  __shared__ float h_sh[Hd];

  const int u   = threadIdx.x;
  const int seq = blockIdx.x;
  h_sh[u] = 0.f;

  float4 wh[4][16];
  #pragma unroll
  for (int g = 0; g < 4; ++g) {
    const float4* wrow = (const float4*)(Whh1 + (g * 64 + u) * Hd);
    #pragma unroll
    for (int q = 0; q < 16; ++q) wh[g][q] = wrow[q];
  }
  float c = 0.f;

  float gc[4];
  #pragma unroll
  for (int g = 0; g < 4; ++g) gc[g] = G1[(seq * Wd + 0) * NG + g * 64 + u];
  __syncthreads();

  for (int t = 0; t < Wd; ++t) {
    float gn[4];
    #pragma unroll
    for (int g = 0; g < 4; ++g)
      gn[g] = (t + 1 < Wd) ? G1[(seq * Wd + t + 1) * NG + g * 64 + u] : 0.f;

    float4 hv[16];
    const float4* h4 = (const float4*)h_sh;
    #pragma unroll
    for (int q = 0; q < 16; ++q) hv[q] = h4[q];              // broadcast

    float g4[4];
    #pragma unroll
    for (int g = 0; g < 4; ++g) {
      float a0 = gc[g];                       // bias folded into G1
      float a1 = 0.f, a2 = 0.f, a3 = 0.f;
      #pragma unroll
      for (int q = 0; q < 16; ++q) {
        float d = hv[q].x * wh[g][q].x + hv[q].y * wh[g][q].y +
                  hv[q].z * wh[g][q].z + hv[q].w * wh[g][q].w;
        if ((q & 3) == 0) a0 += d; else if ((q & 3) == 1) a1 += d;
        else if ((q & 3) == 2) a2 += d; else a3 += d;
      }
      float acc = (a0 + a1) + (a2 + a3);
      g4[g] = (g == 2) ? tanh_fast(acc) : sigm(acc);
    }
    c = g4[1] * c + g4[0] * g4[2];
    float h = g4[3] * tanh_fast(c);
    h_sh[u] = h;
    __syncthreads();                          // 1-wave barrier
    if (t == Wd - 1) hout[seq * Hd + u] = h;
    #pragma unroll
    for (int g = 0; g < 4; ++g) gc[g] = gn[g];
  }
}

// --------------------------------------------------------------------------
// Fused per-row node pipeline: wsum (adj x edge reduce over j) -> GCN round 0
// -> GCN round 1 -> u/v precompute for the edge MLP. One block per row
// (b,i); 256 threads. All arithmetic orders identical to the unfused R4
// kernels (wsum via wave shuffle + 4-way combine; LN via shfl_xor).
__global__ __launch_bounds__(256) void k_node(
    const float* __restrict__ ef,    const float* __restrict__ adj,
    const float* __restrict__ h0,
    const float* __restrict__ gcn_W, const float* __restrict__ gcn_b,
    const float* __restrict__ ep_W,  const float* __restrict__ ep_b,
    const float* __restrict__ ln_g,  const float* __restrict__ ln_b,
    const float* __restrict__ W1,    const float* __restrict__ b1,
    float* __restrict__ uu, float* __restrict__ vt)
{
  __shared__ float red[4][6];
  __shared__ float w6[6];
  __shared__ float hcur[Hd];

  const int row = blockIdx.x;      // b*200+i
  const int b = row / Nd, i = row % Nd;
  const int tid = threadIdx.x;

  // ---- wsum: p[e] = sum_j adj*edge[e], p[5] = sum_j adj
  float p[6] = {0.f, 0.f, 0.f, 0.f, 0.f, 0.f};
  if (tid < Nd) {
    float a = adj[(b * Nd + i) * Nd + tid];
    const float* e = ef + (((b * Wd + (Wd - 1)) * Nd + i) * Nd + tid) * Ed;
    p[5] = a;
    #pragma unroll
    for (int k = 0; k < Ed; ++k) p[k] = a * e[k];
  }
  #pragma unroll
  for (int k = 0; k < 6; ++k) {
    float v = p[k];
    for (int off = 32; off > 0; off >>= 1) v += __shfl_down(v, off);
    p[k] = v;
  }
  if ((tid & 63) == 0) {
    #pragma unroll
    for (int k = 0; k < 6; ++k) red[tid >> 6][k] = p[k];
  }
  __syncthreads();
  if (tid < 6)
    w6[tid] = red[0][tid] + red[1][tid] + red[2][tid] + red[3][tid];
  if (tid < Hd) hcur[tid] = h0[row * Hd + tid];
  __syncthreads();

  // ---- 2 GCN rounds (wave 0 only; LN shuffles span exactly 64 lanes)
  const int u = tid & 63;
  #pragma unroll
  for (int round = 0; round < 2; ++round) {
    float hnew = 0.f;
    if (tid < 64) {
      const float* gw = gcn_W + (round * Hd + u) * Hd;
      const float* ew = ep_W  + (round * Hd + u) * Ed;
      float acc = gcn_b[round * Hd + u] + w6[5] * ep_b[round * Hd + u];
      #pragma unroll
      for (int e = 0; e < Ed; ++e) acc += w6[e] * ew[e];
      #pragma unroll 8
      for (int k = 0; k < Hd; ++k) acc += hcur[k] * gw[k];

      float mu = acc;
      #pragma unroll
      for (int off = 1; off < 64; off <<= 1) mu += __shfl_xor(mu, off);
      mu *= (1.f / 64.f);
      float d = acc - mu;
      float var = d * d;
      #pragma unroll
      for (int off = 1; off < 64; off <<= 1) var += __shfl_xor(var, off);
      var *= (1.f / 64.f);
      float v = d * rsqrtf(var + LNEPS) * ln_g[round * Hd + u] + ln_b[round * Hd + u];
      hnew = fmaxf(v, 0.f);
    }
    __syncthreads();               // all reads of hcur done
    if (tid < 64) hcur[tid] = hnew;
    __syncthreads();
  }

  // ---- u/v precompute (threads 0..127)
  if (tid < 64) {
    const float* wr = W1 + tid * 133;          // cols 0..63 (h_i)
    float acc = b1[tid];
    #pragma unroll 8
    for (int k = 0; k < Hd; ++k) acc += hcur[k] * wr[k];
    uu[row * Hd + tid] = acc;
  } else if (tid < 128) {
    const int n = tid - 64;
    const float* wr = W1 + n * 133 + 64;       // cols 64..127 (h_j)
    float acc = 0.f;
    #pragma unroll 8
    for (int k = 0; k < Hd; ++k) acc += hcur[k] * wr[k];
    vt[n * NSEQ + row] = acc;
  }
}

// --------------------------------------------------------------------------
// Edge MLP: thread per edge. z1[64] lives in VGPRs; W1c/W2/W3/b2 have
// wave-uniform indices -> scalar-pipe loads, fmac v,s,v at VALU issue peak.
__global__ __launch_bounds__(256) void k_mlp(
    const float* __restrict__ ef,
    const float* __restrict__ u, const float* __restrict__ vt,
    const float* __restrict__ W1,
    const float* __restrict__ W2, const float* __restrict__ b2,
    const float* __restrict__ W3, const float* __restrict__ b3,
    float* __restrict__ out)
{
  const int idx = blockIdx.x * 256 + threadIdx.x;   // < 320000
  const int b   = idx / (Nd * Nd);
  const int rem = idx - b * Nd * Nd;
  const int i   = rem / Nd;
  const int jj  = rem - i * Nd;

  const float* e = ef + (((b * Wd + (Wd - 1)) * Nd + i) * Nd + jj) * Ed;
  float e5[Ed];
  #pragma unroll
  for (int q = 0; q < Ed; ++q) e5[q] = e[q];

  const float* ur = u + (b * Nd + i) * Hd;
  const int vcol = b * Nd + jj;

  float z1[64];
  #pragma unroll
  for (int k = 0; k < 64; ++k) {
    float acc = ur[k] + vt[k * NSEQ + vcol];
    const float* w1c = W1 + k * 133 + 128;      // uniform -> scalar loads
    #pragma unroll
    for (int q = 0; q < Ed; ++q) acc += e5[q] * w1c[q];
    z1[k] = fmaxf(acc, 0.f);
  }

  float logit = b3[0];
  #pragma unroll 4
  for (int o = 0; o < 32; ++o) {
    float a0 = b2[o], a1 = 0.f, a2 = 0.f, a3 = 0.f;
    const float* w2 = W2 + o * 64;              // uniform -> scalar loads
    #pragma unroll
    for (int k = 0; k < 64; k += 4) {
      a0 += w2[k]     * z1[k];
      a1 += w2[k + 1] * z1[k + 1];
      a2 += w2[k + 2] * z1[k + 2];
      a3 += w2[k + 3] * z1[k + 3];
    }
    float z2 = fmaxf((a0 + a1) + (a2 + a3), 0.f);
    logit += W3[o] * z2;
  }
  out[idx] = 1.f / (1.f + __expf(-logit));
}

// --------------------------------------------------------------------------
extern "C" void kernel_launch(void* const* d_in, const int* in_sizes, int n_in,
                              void* d_out, int out_size, void* d_ws, size_t ws_size,
                              hipStream_t stream) {
  (void)in_sizes; (void)n_in; (void)out_size; (void)ws_size;
  const float* nf   = (const float*)d_in[0];
  const float* ef   = (const float*)d_in[1];
  const float* adj  = (const float*)d_in[2];
  const float* Wih0 = (const float*)d_in[3];
  const float* Whh0 = (const float*)d_in[4];
  const float* bih0 = (const float*)d_in[5];
  const float* bhh0 = (const float*)d_in[6];
  const float* Wih1 = (const float*)d_in[7];
  const float* Whh1 = (const float*)d_in[8];
  const float* bih1 = (const float*)d_in[9];
  const float* bhh1 = (const float*)d_in[10];
  const float* gcnW = (const float*)d_in[11];
  const float* gcnB = (const float*)d_in[12];
  const float* epW  = (const float*)d_in[13];
  const float* epB  = (const float*)d_in[14];
  const float* lnG  = (const float*)d_in[15];
  const float* lnB  = (const float*)d_in[16];
  const float* W1   = (const float*)d_in[17];
  const float* b1   = (const float*)d_in[18];
  const float* W2   = (const float*)d_in[19];
  const float* b2   = (const float*)d_in[20];
  const float* W3   = (const float*)d_in[21];
  const float* b3   = (const float*)d_in[22];
  float* out = (float*)d_out;

  // Workspace layout (floats).
  float* ws  = (float*)d_ws;
  float* y0  = ws;                         // 1600*12*64 = 1,228,800
  float* G1  = y0  + 1228800;              // 19200*256  = 4,915,200
  float* Wt1 = G1  + 4915200;              // 64*256     = 16,384
  float* h0  = Wt1 + 16384;                // 1600*64    = 102,400
  float* uu  = h0  + 102400;               // 102,400
  float* vt  = uu  + 102400;               // 102,400

  k_prep  <<<64,   256, 0, stream>>>(Wih1, Wt1);
  k_lstm0 <<<NSEQ, 64,  0, stream>>>(nf, Wih0, Whh0, bih0, bhh0, y0);
  k_xproj1<<<300,  256, 0, stream>>>(y0, Wt1, bih1, bhh1, G1);
  k_lstm1 <<<NSEQ, 64,  0, stream>>>(G1, Whh1, h0);
  k_node  <<<1600, 256, 0, stream>>>(ef, adj, h0, gcnW, gcnB, epW, epB,
                                     lnG, lnB, W1, b1, uu, vt);
  k_mlp   <<<1250, 256, 0, stream>>>(ef, uu, vt, W1, W2, b2, W3, b3, out);
}

// Round 6
// 282.515 us; speedup vs baseline: 1.0962x; 1.0962x over previous
//
#include <hip/hip_runtime.h>
#include <math.h>

// ---------------------------------------------------------------------------
// TemporalGCN: 2-layer LSTM (per-node sequences) -> 2 GCN rounds -> edge MLP.
//
// R5 post-mortem: one-wave-per-seq needed 256 weight VGPRs; compiler capped
// at 220 and REMATERIALIZED the weight loads every timestep (VGPR_Count=220,
// VALUBusy 31%, 65 us). Retro-audit: R2's VGPR=52 shows weights were never
// register-resident in ANY round. R6: back to 1-gate-row/thread (64 weight
// VGPRs) with (a) inline-asm pin forcing the 16 float4 weights to stay in
// registers, (b) ONE barrier/step: all waves redundantly compute the c/h
// update (each wave covers u=0..63, reads only self-written LDS; cross-wave
// dup writes are identical-value), gate_sh double-buffered to kill the WAR
// race the 2nd barrier used to guard.
// ---------------------------------------------------------------------------

#define Hd   64
#define Ed   5
#define Fd   6
#define Bd   8
#define Wd   12
#define Nd   200
#define NSEQ (Bd*Nd)        // 1600 sequences (b,n)
#define NG   (4*Hd)         // 256 gate rows
#define NEDGE (Bd*Nd*Nd)    // 320000 edges
#define LNEPS 1e-5f

// Pin a float4's components into VGPRs: makes the asm the value's producer,
// so the compiler cannot re-load it from memory inside the loop.
#define PIN4(v) asm volatile("" : "+v"((v).x), "+v"((v).y), "+v"((v).z), "+v"((v).w))

__device__ __forceinline__ float sigm(float x) { return 1.0f / (1.0f + __expf(-x)); }
__device__ __forceinline__ float tanh_fast(float x) {
  float ax = fabsf(x);
  float t  = __expf(-2.0f * ax);
  float r  = (1.0f - t) / (1.0f + t);
  return copysignf(r, x);
}

// --------------------------------------------------------------------------
// Transpose Wih1 (256x64) -> Wt1 (64x256) so xproj1 can do contiguous
// scalar loads of a k-row.
__global__ __launch_bounds__(256) void k_prep(const float* __restrict__ Wih1,
                                              float* __restrict__ Wt1) {
  int k = blockIdx.x;          // 0..63
  int j = threadIdx.x;         // 0..255
  Wt1[k * NG + j] = Wih1[j * Hd + k];
}

// --------------------------------------------------------------------------
// LSTM layer 0. 1600 blocks x 256 threads; block owns ONE sequence.
// Thread j = gate row j; its 64 weights pinned in VGPRs. One barrier/step.
__global__ __launch_bounds__(256, 3) void k_lstm0(
    const float* __restrict__ nf,                       // (B,W,N,F)
    const float* __restrict__ Wih0, const float* __restrict__ Whh0,
    const float* __restrict__ bih0, const float* __restrict__ bhh0,
    float* __restrict__ y0)                             // (NSEQ, W, H)
{
  __shared__ float x_sh[Wd * Fd];     // 72
  __shared__ float h_sh[Hd];          // 64
  __shared__ float gate_sh[2][NG];    // double-buffered post-activation gates

  const int tid = threadIdx.x;
  const int seq = blockIdx.x;
  const int b = seq / Nd, n = seq % Nd;
  const int u = tid & 63;

  if (tid < Wd * Fd) {
    int t = tid / Fd, f = tid % Fd;
    x_sh[tid] = nf[((b * Wd + t) * Nd + n) * Fd + f];
  }
  h_sh[u] = 0.f;                      // 4x dup write of identical value

  const int j = tid;
  float4 wh[16];
  const float4* wrow = (const float4*)(Whh0 + j * Hd);
  #pragma unroll
  for (int q = 0; q < 16; ++q) { wh[q] = wrow[q]; PIN4(wh[q]); }
  float wx[Fd];
  #pragma unroll
  for (int f = 0; f < Fd; ++f) wx[f] = Wih0[j * Fd + f];
  const float bias = bih0[j] + bhh0[j];
  const int jt = j >> 6;              // 0=i,1=f,2=g,3=o (wave-uniform)

  float c = 0.f;                      // cell state for unit u (per-wave copy)
  __syncthreads();

  for (int t = 0; t < Wd; ++t) {
    // fma phase: reads h_sh (self-written last iter) + x broadcast
    const float* xp = x_sh + t * Fd;
    float a0 = bias, a1 = 0.f, a2 = 0.f, a3 = 0.f;
    #pragma unroll
    for (int f = 0; f < Fd; ++f) a1 += xp[f] * wx[f];
    const float4* h4 = (const float4*)h_sh;
    #pragma unroll
    for (int q = 0; q < 16; ++q) {
      float4 hv = h4[q];
      float d = hv.x * wh[q].x + hv.y * wh[q].y + hv.z * wh[q].z + hv.w * wh[q].w;
      if ((q & 3) == 0) a0 += d; else if ((q & 3) == 1) a1 += d;
      else if ((q & 3) == 2) a2 += d; else a3 += d;
    }
    float acc = (a0 + a1) + (a2 + a3);
    gate_sh[t & 1][j] = (jt == 2) ? tanh_fast(acc) : sigm(acc);
    __syncthreads();                  // the ONLY barrier per step
    // redundant c/h update: every wave covers u=0..63
    const float* gb = gate_sh[t & 1];
    float iv = gb[u];
    float fv = gb[64 + u];
    float gv = gb[128 + u];
    float ov = gb[192 + u];
    c = fv * c + iv * gv;
    float h = ov * tanh_fast(c);
    h_sh[u] = h;                      // dup identical-value writes: benign
    if (tid < Hd) y0[seq * (Wd * Hd) + t * Hd + u] = h;
  }
}

// --------------------------------------------------------------------------
// G1 = y0 @ Wih1.T + (bih1+bhh1): (19200 x 64) @ (64 x 256).
// 300 blocks x 256 thr; lane = row, wave = 64-col slab (wave-uniform cols ->
// weights via SCALAR loads; VALU-bound). Output transposed through a 2-tile
// osh in two passes (LDS total 49.9 KB < 64 KB static limit).
__global__ __launch_bounds__(256) void k_xproj1(
    const float* __restrict__ y0,    // rows = seq*12+t
    const float* __restrict__ Wt1,   // (64,256) transposed Wih1
    const float* __restrict__ bih1, const float* __restrict__ bhh1,
    float* __restrict__ G1)          // (19200, 256)
{
  __shared__ float ysh[64 * 65];        // [r][k] pad-65: conflict-free
  __shared__ float osh[2 * 64 * 65];    // two 64x64 out tiles, pad-65

  const int tid  = threadIdx.x;
  const int row0 = blockIdx.x * 64;
  for (int idx = tid; idx < 64 * 64; idx += 256) {
    int r = idx >> 6, k = idx & 63;
    ysh[r * 65 + k] = y0[(row0 + r) * Hd + k];
  }
  __syncthreads();

  const int w = __builtin_amdgcn_readfirstlane(tid >> 6);  // force uniform
  const int r = tid & 63;
  float acc[64];
  #pragma unroll
  for (int c = 0; c < 64; ++c) acc[c] = 0.f;

  const float* wbase = Wt1 + (w << 6);
  #pragma unroll 2
  for (int k = 0; k < 64; ++k) {
    float yv = ysh[r * 65 + k];
    const float* wk = wbase + k * NG;    // uniform address -> s_load
    #pragma unroll
    for (int c = 0; c < 64; ++c) acc[c] = fmaf(yv, wk[c], acc[c]);
  }
  #pragma unroll
  for (int c = 0; c < 64; ++c) acc[c] += bih1[(w << 6) + c] + bhh1[(w << 6) + c];

  // Two passes: waves {0,1} then {2,3} dump 64x64 tiles; everyone stores.
  #pragma unroll
  for (int p = 0; p < 2; ++p) {
    __syncthreads();
    if ((w >> 1) == p) {
      float* orow = osh + ((w & 1) * 64 + r) * 65;
      #pragma unroll
      for (int c = 0; c < 64; ++c) orow[c] = acc[c];  // stride-65: no conflict
    }
    __syncthreads();
    for (int idx = tid; idx < 2 * 64 * 64; idx += 256) {
      int c  = idx & 127;              // col within this 128-col slab
      int rr = idx >> 7;               // row 0..63
      G1[(row0 + rr) * NG + p * 128 + c] =
          osh[((c >> 6) * 64 + rr) * 65 + (c & 63)];   // lanes stride-1: free
    }
  }
}

// --------------------------------------------------------------------------
// LSTM layer 1 recurrence (K=64; input proj precomputed in G1). 1600 blocks
// x 256 threads, same single-barrier structure as k_lstm0; weights pinned;
// G1 row prefetched one timestep ahead (1 coalesced dword per thread).
__global__ __launch_bounds__(256, 3) void k_lstm1(
    const float* __restrict__ G1,
    const float* __restrict__ Whh1,
    float* __restrict__ hout)        // (NSEQ, H)
{
  __shared__ float h_sh[Hd];
  __shared__ float gate_sh[2][NG];

  const int tid = threadIdx.x;
  const int seq = blockIdx.x;
  const int u = tid & 63;
  h_sh[u] = 0.f;

  const int j = tid;
  float4 wh[16];
  const float4* wrow = (const float4*)(Whh1 + j * Hd);
  #pragma unroll
  for (int q = 0; q < 16; ++q) { wh[q] = wrow[q]; PIN4(wh[q]); }
  const int jt = j >> 6;
  float c = 0.f;

  float g_cur = G1[(seq * Wd + 0) * NG + j];   // prefetch t=0
  __syncthreads();

  for (int t = 0; t < Wd; ++t) {
    float g_next = (t + 1 < Wd) ? G1[(seq * Wd + t + 1) * NG + j] : 0.f;
    float a0 = g_cur;                          // bias folded into G1
    float a1 = 0.f, a2 = 0.f, a3 = 0.f;
    const float4* h4 = (const float4*)h_sh;
    #pragma unroll
    for (int q = 0; q < 16; ++q) {
      float4 hv = h4[q];
      float d = hv.x * wh[q].x + hv.y * wh[q].y + hv.z * wh[q].z + hv.w * wh[q].w;
      if ((q & 3) == 0) a0 += d; else if ((q & 3) == 1) a1 += d;
      else if ((q & 3) == 2) a2 += d; else a3 += d;
    }
    float acc = (a0 + a1) + (a2 + a3);
    gate_sh[t & 1][j] = (jt == 2) ? tanh_fast(acc) : sigm(acc);
    __syncthreads();                  // the ONLY barrier per step
    const float* gb = gate_sh[t & 1];
    float iv = gb[u];
    float fv = gb[64 + u];
    float gv = gb[128 + u];
    float ov = gb[192 + u];
    c = fv * c + iv * gv;
    float h = ov * tanh_fast(c);
    h_sh[u] = h;
    if (t == Wd - 1 && tid < Hd) hout[seq * Hd + u] = h;
    g_cur = g_next;
  }
}

// --------------------------------------------------------------------------
// Fused per-row node pipeline: wsum (adj x edge reduce over j) -> GCN round 0
// -> GCN round 1 -> u/v precompute for the edge MLP. One block per row
// (b,i); 256 threads. All arithmetic orders identical to the unfused R4
// kernels (wsum via wave shuffle + 4-way combine; LN via shfl_xor).
__global__ __launch_bounds__(256) void k_node(
    const float* __restrict__ ef,    const float* __restrict__ adj,
    const float* __restrict__ h0,
    const float* __restrict__ gcn_W, const float* __restrict__ gcn_b,
    const float* __restrict__ ep_W,  const float* __restrict__ ep_b,
    const float* __restrict__ ln_g,  const float* __restrict__ ln_b,
    const float* __restrict__ W1,    const float* __restrict__ b1,
    float* __restrict__ uu, float* __restrict__ vt)
{
  __shared__ float red[4][6];
  __shared__ float w6[6];
  __shared__ float hcur[Hd];

  const int row = blockIdx.x;      // b*200+i
  const int b = row / Nd, i = row % Nd;
  const int tid = threadIdx.x;

  // ---- wsum: p[e] = sum_j adj*edge[e], p[5] = sum_j adj
  float p[6] = {0.f, 0.f, 0.f, 0.f, 0.f, 0.f};
  if (tid < Nd) {
    float a = adj[(b * Nd + i) * Nd + tid];
    const float* e = ef + (((b * Wd + (Wd - 1)) * Nd + i) * Nd + tid) * Ed;
    p[5] = a;
    #pragma unroll
    for (int k = 0; k < Ed; ++k) p[k] = a * e[k];
  }
  #pragma unroll
  for (int k = 0; k < 6; ++k) {
    float v = p[k];
    for (int off = 32; off > 0; off >>= 1) v += __shfl_down(v, off);
    p[k] = v;
  }
  if ((tid & 63) == 0) {
    #pragma unroll
    for (int k = 0; k < 6; ++k) red[tid >> 6][k] = p[k];
  }
  __syncthreads();
  if (tid < 6)
    w6[tid] = red[0][tid] + red[1][tid] + red[2][tid] + red[3][tid];
  if (tid < Hd) hcur[tid] = h0[row * Hd + tid];
  __syncthreads();

  // ---- 2 GCN rounds (wave 0 only; LN shuffles span exactly 64 lanes)
  const int u = tid & 63;
  #pragma unroll
  for (int round = 0; round < 2; ++round) {
    float hnew = 0.f;
    if (tid < 64) {
      const float* gw = gcn_W + (round * Hd + u) * Hd;
      const float* ew = ep_W  + (round * Hd + u) * Ed;
      float acc = gcn_b[round * Hd + u] + w6[5] * ep_b[round * Hd + u];
      #pragma unroll
      for (int e = 0; e < Ed; ++e) acc += w6[e] * ew[e];
      #pragma unroll 8
      for (int k = 0; k < Hd; ++k) acc += hcur[k] * gw[k];

      float mu = acc;
      #pragma unroll
      for (int off = 1; off < 64; off <<= 1) mu += __shfl_xor(mu, off);
      mu *= (1.f / 64.f);
      float d = acc - mu;
      float var = d * d;
      #pragma unroll
      for (int off = 1; off < 64; off <<= 1) var += __shfl_xor(var, off);
      var *= (1.f / 64.f);
      float v = d * rsqrtf(var + LNEPS) * ln_g[round * Hd + u] + ln_b[round * Hd + u];
      hnew = fmaxf(v, 0.f);
    }
    __syncthreads();               // all reads of hcur done
    if (tid < 64) hcur[tid] = hnew;
    __syncthreads();
  }

  // ---- u/v precompute (threads 0..127)
  if (tid < 64) {
    const float* wr = W1 + tid * 133;          // cols 0..63 (h_i)
    float acc = b1[tid];
    #pragma unroll 8
    for (int k = 0; k < Hd; ++k) acc += hcur[k] * wr[k];
    uu[row * Hd + tid] = acc;
  } else if (tid < 128) {
    const int n = tid - 64;
    const float* wr = W1 + n * 133 + 64;       // cols 64..127 (h_j)
    float acc = 0.f;
    #pragma unroll 8
    for (int k = 0; k < Hd; ++k) acc += hcur[k] * wr[k];
    vt[n * NSEQ + row] = acc;
  }
}

// --------------------------------------------------------------------------
// Edge MLP: thread per edge. z1[64] lives in VGPRs; W1c/W2/W3/b2 have
// wave-uniform indices -> scalar-pipe loads, fmac v,s,v at VALU issue peak.
__global__ __launch_bounds__(256) void k_mlp(
    const float* __restrict__ ef,
    const float* __restrict__ u, const float* __restrict__ vt,
    const float* __restrict__ W1,
    const float* __restrict__ W2, const float* __restrict__ b2,
    const float* __restrict__ W3, const float* __restrict__ b3,
    float* __restrict__ out)
{
  const int idx = blockIdx.x * 256 + threadIdx.x;   // < 320000
  const int b   = idx / (Nd * Nd);
  const int rem = idx - b * Nd * Nd;
  const int i   = rem / Nd;
  const int jj  = rem - i * Nd;

  const float* e = ef + (((b * Wd + (Wd - 1)) * Nd + i) * Nd + jj) * Ed;
  float e5[Ed];
  #pragma unroll
  for (int q = 0; q < Ed; ++q) e5[q] = e[q];

  const float* ur = u + (b * Nd + i) * Hd;
  const int vcol = b * Nd + jj;

  float z1[64];
  #pragma unroll
  for (int k = 0; k < 64; ++k) {
    float acc = ur[k] + vt[k * NSEQ + vcol];
    const float* w1c = W1 + k * 133 + 128;      // uniform -> scalar loads
    #pragma unroll
    for (int q = 0; q < Ed; ++q) acc += e5[q] * w1c[q];
    z1[k] = fmaxf(acc, 0.f);
  }

  float logit = b3[0];
  #pragma unroll 4
  for (int o = 0; o < 32; ++o) {
    float a0 = b2[o], a1 = 0.f, a2 = 0.f, a3 = 0.f;
    const float* w2 = W2 + o * 64;              // uniform -> scalar loads
    #pragma unroll
    for (int k = 0; k < 64; k += 4) {
      a0 += w2[k]     * z1[k];
      a1 += w2[k + 1] * z1[k + 1];
      a2 += w2[k + 2] * z1[k + 2];
      a3 += w2[k + 3] * z1[k + 3];
    }
    float z2 = fmaxf((a0 + a1) + (a2 + a3), 0.f);
    logit += W3[o] * z2;
  }
  out[idx] = 1.f / (1.f + __expf(-logit));
}

// --------------------------------------------------------------------------
extern "C" void kernel_launch(void* const* d_in, const int* in_sizes, int n_in,
                              void* d_out, int out_size, void* d_ws, size_t ws_size,
                              hipStream_t stream) {
  (void)in_sizes; (void)n_in; (void)out_size; (void)ws_size;
  const float* nf   = (const float*)d_in[0];
  const float* ef   = (const float*)d_in[1];
  const float* adj  = (const float*)d_in[2];
  const float* Wih0 = (const float*)d_in[3];
  const float* Whh0 = (const float*)d_in[4];
  const float* bih0 = (const float*)d_in[5];
  const float* bhh0 = (const float*)d_in[6];
  const float* Wih1 = (const float*)d_in[7];
  const float* Whh1 = (const float*)d_in[8];
  const float* bih1 = (const float*)d_in[9];
  const float* bhh1 = (const float*)d_in[10];
  const float* gcnW = (const float*)d_in[11];
  const float* gcnB = (const float*)d_in[12];
  const float* epW  = (const float*)d_in[13];
  const float* epB  = (const float*)d_in[14];
  const float* lnG  = (const float*)d_in[15];
  const float* lnB  = (const float*)d_in[16];
  const float* W1   = (const float*)d_in[17];
  const float* b1   = (const float*)d_in[18];
  const float* W2   = (const float*)d_in[19];
  const float* b2   = (const float*)d_in[20];
  const float* W3   = (const float*)d_in[21];
  const float* b3   = (const float*)d_in[22];
  float* out = (float*)d_out;

  // Workspace layout (floats).
  float* ws  = (float*)d_ws;
  float* y0  = ws;                         // 1600*12*64 = 1,228,800
  float* G1  = y0  + 1228800;              // 19200*256  = 4,915,200
  float* Wt1 = G1  + 4915200;              // 64*256     = 16,384
  float* h0  = Wt1 + 16384;                // 1600*64    = 102,400
  float* uu  = h0  + 102400;               // 102,400
  float* vt  = uu  + 102400;               // 102,400

  k_prep  <<<64,   256, 0, stream>>>(Wih1, Wt1);
  k_lstm0 <<<NSEQ, 256, 0, stream>>>(nf, Wih0, Whh0, bih0, bhh0, y0);
  k_xproj1<<<300,  256, 0, stream>>>(y0, Wt1, bih1, bhh1, G1);
  k_lstm1 <<<NSEQ, 256, 0, stream>>>(G1, Whh1, h0);
  k_node  <<<1600, 256, 0, stream>>>(ef, adj, h0, gcnW, gcnB, epW, epB,
                                     lnG, lnB, W1, b1, uu, vt);
  k_mlp   <<<1250, 256, 0, stream>>>(ef, uu, vt, W1, W2, b2, W3, b3, out);
}